// Round 9
// baseline (1551.162 us; speedup 1.0000x reference)
//
#include <hip/hip_runtime.h>
#include <hip/hip_fp16.h>

#define NN 100000
#define NE 1600000
#define KORD 10
#define HID 64
#define SCAN_BLK 1024
#define NBLK ((NN + SCAN_BLK - 1) / SCAN_BLK)   // 98
#define BSHIFT 7
#define BNODES 128
#define NB ((NN + BNODES - 1) / BNODES)          // 782 buckets
#define BCAP 4608                                 // LDS edge cap per bucket (mean 2048, sd 45)

typedef _Float16 half8v __attribute__((ext_vector_type(8)));
typedef _Float16 half4v __attribute__((ext_vector_type(4)));
typedef float float4v __attribute__((ext_vector_type(4)));

__device__ __forceinline__ float2 up2(unsigned u) {
    __half2 hh = *(__half2*)&u;
    return __half22float2(hh);
}
__device__ __forceinline__ unsigned pk2(float a, float b) {
    __half2 hh = __floats2half2_rn(a, b);
    return *(unsigned*)&hh;
}

// ---------------- degree / scan ----------------
__global__ __launch_bounds__(256) void k_zero(int* __restrict__ cnt) {
    int i = blockIdx.x * 256 + threadIdx.x;
    if (i < NN) cnt[i] = 0;
}

__global__ __launch_bounds__(256) void k_hist(const int* __restrict__ ei,
                                              int* __restrict__ cnt) {
    int e = blockIdx.x * 256 + threadIdx.x;
    if (e < NE) atomicAdd(&cnt[ei[NE + e]], 1);
}

__global__ __launch_bounds__(256) void k_dinv(const int* __restrict__ cnt,
                                              float* __restrict__ dinv) {
    int i = blockIdx.x * 256 + threadIdx.x;
    if (i < NN) dinv[i] = rsqrtf((float)(cnt[i] + 1));   // +1 self-loop
}

__global__ __launch_bounds__(SCAN_BLK) void k_scan1(const int* __restrict__ cnt,
                                                    int* __restrict__ cursor,
                                                    int* __restrict__ bsum) {
    __shared__ int tmp[SCAN_BLK];
    int t = threadIdx.x;
    int g = blockIdx.x * SCAN_BLK + t;
    int v = (g < NN) ? cnt[g] : 0;
    tmp[t] = v;
    __syncthreads();
    int x = v;
    for (int off = 1; off < SCAN_BLK; off <<= 1) {
        int y = (t >= off) ? tmp[t - off] : 0;
        __syncthreads();
        x += y;
        tmp[t] = x;
        __syncthreads();
    }
    if (g < NN) cursor[g] = x - v;
    if (t == SCAN_BLK - 1) bsum[blockIdx.x] = x;
}

__global__ __launch_bounds__(128) void k_scan2(int* __restrict__ bsum) {
    __shared__ int tmp[128];
    int t = threadIdx.x;
    int v = (t < NBLK) ? bsum[t] : 0;
    tmp[t] = v;
    __syncthreads();
    int x = v;
    for (int off = 1; off < 128; off <<= 1) {
        int y = (t >= off) ? tmp[t - off] : 0;
        __syncthreads();
        x += y;
        tmp[t] = x;
        __syncthreads();
    }
    if (t < NBLK) bsum[t] = x - v;
}

__global__ __launch_bounds__(SCAN_BLK) void k_scan3(int* __restrict__ cursor,
                                                    const int* __restrict__ bsum) {
    int g = blockIdx.x * SCAN_BLK + threadIdx.x;
    if (g < NN) cursor[g] += bsum[blockIdx.x];
    if (g == 0) cursor[NN] = NE;          // sentinel end offset
}

// ---------------- bucketed CSR build ----------------
__global__ __launch_bounds__(256) void k_binit(const int* __restrict__ cursor,
                                               int* __restrict__ bcur) {
    int b = blockIdx.x * 256 + threadIdx.x;
    if (b < NB) bcur[b] = cursor[b << BSHIFT];
}

// phase A: append (src,dst) into dest-bucket regions (line-dense writes)
__global__ __launch_bounds__(256) void k_bucket(const int* __restrict__ ei,
                                                int* __restrict__ bcur,
                                                int2* __restrict__ bkt) {
    int e = blockIdx.x * 256 + threadIdx.x;
    if (e >= NE) return;
    int r = ei[e], c = ei[NE + e];
    int pos = atomicAdd(&bcur[c >> BSHIFT], 1);
    bkt[pos] = make_int2(r, c);
}

// phase B: one block per bucket; sort bucket into per-node CSR order via LDS
__global__ __launch_bounds__(256) void k_build(const int* __restrict__ cursor,
                                               const int2* __restrict__ bkt,
                                               int* __restrict__ csr) {
    __shared__ int lcur[BNODES];
    __shared__ int lcsr[BCAP];
    int b = blockIdx.x;
    int t = threadIdx.x;
    int node0 = b << BSHIFT;
    int node1 = min(node0 + BNODES, NN);
    int ebase = cursor[node0];
    int eend  = cursor[node1];
    int cnt = eend - ebase;
    if (t < BNODES) {
        int idx = min(node0 + t, NN);
        lcur[t] = cursor[idx] - ebase;
    }
    __syncthreads();
    for (int j = ebase + t; j < eend; j += 256) {
        int2 pr = bkt[j];
        int pos = atomicAdd(&lcur[pr.y - node0], 1);
        if (pos < BCAP) lcsr[pos] = pr.x;     // cap guard (P(overflow) ~ 0)
    }
    __syncthreads();
    for (int j = t; j < cnt; j += 256) csr[ebase + j] = lcsr[j];
}

// ---------- W1 transpose + fp16 cast ----------
__global__ __launch_bounds__(256) void k_prepw1(const float* __restrict__ W1,
                                                _Float16* __restrict__ W1T) {
    int f = blockIdx.x * 256 + threadIdx.x;
    int n = f >> 8, k = f & 255;
    W1T[f] = (_Float16)W1[k * 64 + n];
}

// ---------- GEMM1 via MFMA: h~ = dinv * relu(x @ W1 + b1) ----------
#define G1K 128
#define G1S 136
__global__ __launch_bounds__(256) void k_gemm1(const float* __restrict__ x,
                                               const _Float16* __restrict__ W1T,
                                               const float* __restrict__ b1,
                                               const float* __restrict__ dinv,
                                               __half* __restrict__ h) {
    __shared__ _Float16 A_lds[64 * G1S];
    __shared__ _Float16 B_lds[64 * G1S];
    int t = threadIdx.x;
    int wave = t >> 6, lane = t & 63;
    int quad = lane >> 4, m16 = lane & 15;
    int row0 = blockIdx.x * 64;

    float4v acc[4];
#pragma unroll
    for (int n4 = 0; n4 < 4; ++n4) acc[n4] = (float4v){0.f, 0.f, 0.f, 0.f};

    for (int c = 0; c < 2; ++c) {
        int k0 = c * G1K;
#pragma unroll
        for (int i = 0; i < 8; ++i) {
            int f = i * 256 + t;
            int r = f >> 5, c4 = f & 31;
            int grow = row0 + r;
            float4 v = (grow < NN) ? *(const float4*)&x[(size_t)grow * 256 + k0 + c4 * 4]
                                   : make_float4(0.f, 0.f, 0.f, 0.f);
            half4v hv = {(_Float16)v.x, (_Float16)v.y, (_Float16)v.z, (_Float16)v.w};
            *(half4v*)&A_lds[r * G1S + c4 * 4] = hv;
        }
#pragma unroll
        for (int i = 0; i < 4; ++i) {
            int f = i * 256 + t;
            int n = f >> 4, k8 = f & 15;
            *(half8v*)&B_lds[n * G1S + k8 * 8] =
                *(const half8v*)&W1T[n * 256 + k0 + k8 * 8];
        }
        __syncthreads();

#pragma unroll
        for (int s = 0; s < 4; ++s) {
            half8v af = *(const half8v*)&A_lds[(wave * 16 + m16) * G1S + s * 32 + quad * 8];
#pragma unroll
            for (int n4 = 0; n4 < 4; ++n4) {
                half8v bf = *(const half8v*)&B_lds[(n4 * 16 + m16) * G1S + s * 32 + quad * 8];
                acc[n4] = __builtin_amdgcn_mfma_f32_16x16x32_f16(af, bf, acc[n4], 0, 0, 0);
            }
        }
        __syncthreads();
    }

    float bv[4];
#pragma unroll
    for (int n4 = 0; n4 < 4; ++n4) bv[n4] = b1[n4 * 16 + m16];
#pragma unroll
    for (int r = 0; r < 4; ++r) {
        int grow = row0 + wave * 16 + quad * 4 + r;
        if (grow >= NN) continue;
        float dv = dinv[grow];
#pragma unroll
        for (int n4 = 0; n4 < 4; ++n4) {
            float v = dv * fmaxf(acc[n4][r] + bv[n4], 0.f);
            h[(size_t)grow * 64 + n4 * 16 + m16] = __float2half(v);
        }
    }
}

// ---------- fused propagation + Jacobi combine, 8 nodes per wave ----------
// lane: nd = lane>>3 (node in wave), ch8 = (lane&7)*8 halves (16B of channels).
// No cross-lane reduction; every lane runs the epilogue for its own node.
// Two edge streams per lane (split range) keep 2 gathers in flight.
__global__ __launch_bounds__(256) void k_prop(const int* __restrict__ cursor,   // begin offsets, cursor[NN]=NE
                                              const int* __restrict__ csr,
                                              const __half* __restrict__ src,
                                              const __half* __restrict__ t0,
                                              const float* __restrict__ dinv,
                                              __half* __restrict__ dst,
                                              __half* __restrict__ acc,
                                              __half* __restrict__ hout,
                                              float An, float Bn, float Cn,
                                              const float* __restrict__ coeffs,
                                              int cbase, int kidx, int init,
                                              int finalize, int unscale) {
    int wid = (blockIdx.x * 256 + threadIdx.x) >> 6;
    int lane = threadIdx.x & 63;
    int node = wid * 8 + (lane >> 3);
    int ch8 = (lane & 7) * 8;
    bool valid = node < NN;
    int beg = valid ? cursor[node] : 0;
    int end = valid ? cursor[node + 1] : 0;
    int mid = (beg + end) >> 1;

    float p[8];
#pragma unroll
    for (int i = 0; i < 8; ++i) p[i] = 0.f;

    int jA = beg, jB = mid;
    while (__any((jA < mid) | (jB < end))) {
        if (jA < mid) {
            int r = csr[jA];
            union { uint4 u; __half h[8]; } U;
            U.u = *(const uint4*)&src[(size_t)r * HID + ch8];
#pragma unroll
            for (int i = 0; i < 8; ++i) p[i] += __half2float(U.h[i]);
        }
        if (jB < end) {
            int r = csr[jB];
            union { uint4 u; __half h[8]; } U;
            U.u = *(const uint4*)&src[(size_t)r * HID + ch8];
#pragma unroll
            for (int i = 0; i < 8; ++i) p[i] += __half2float(U.h[i]);
        }
        ++jA; ++jB;
    }

    if (!valid) return;
    size_t idx = (size_t)node * HID + ch8;
    float dv = dinv[node];
    float dv2 = dv * dv;

    uint4 sr = *(const uint4*)&src[idx];
    float2 s01 = up2(sr.x), s23 = up2(sr.y), s45 = up2(sr.z), s67 = up2(sr.w);
    float sv[8] = {s01.x, s01.y, s23.x, s23.y, s45.x, s45.y, s67.x, s67.y};

    uint4 tr = *(const uint4*)&t0[idx];
    float2 t01 = up2(tr.x), t23 = up2(tr.y), t45 = up2(tr.z), t67 = up2(tr.w);
    float tv[8] = {t01.x, t01.y, t23.x, t23.y, t45.x, t45.y, t67.x, t67.y};

    float v[8];
#pragma unroll
    for (int i = 0; i < 8; ++i)
        v[i] = An * dv2 * (p[i] + sv[i]) + Bn * sv[i] - Cn * tv[i];

    if (!finalize) {
        uint4 o;
        o.x = pk2(v[0], v[1]); o.y = pk2(v[2], v[3]);
        o.z = pk2(v[4], v[5]); o.w = pk2(v[6], v[7]);
        *(uint4*)&dst[idx] = o;
    }

    float ck = coeffs[cbase + kidx];
    float av[8];
    if (init) {
        float c0 = coeffs[cbase];
#pragma unroll
        for (int i = 0; i < 8; ++i) av[i] = c0 * sv[i];
    } else {
        uint4 ar = *(const uint4*)&acc[idx];
        float2 a01 = up2(ar.x), a23 = up2(ar.y), a45 = up2(ar.z), a67 = up2(ar.w);
        av[0] = a01.x; av[1] = a01.y; av[2] = a23.x; av[3] = a23.y;
        av[4] = a45.x; av[5] = a45.y; av[6] = a67.x; av[7] = a67.y;
    }
#pragma unroll
    for (int i = 0; i < 8; ++i) av[i] += ck * v[i];

    uint4 o;
    if (finalize) {
        float s = unscale ? (1.0f / dv) : 1.0f;
        o.x = pk2(s * fmaxf(av[0], 0.f), s * fmaxf(av[1], 0.f));
        o.y = pk2(s * fmaxf(av[2], 0.f), s * fmaxf(av[3], 0.f));
        o.z = pk2(s * fmaxf(av[4], 0.f), s * fmaxf(av[5], 0.f));
        o.w = pk2(s * fmaxf(av[6], 0.f), s * fmaxf(av[7], 0.f));
        *(uint4*)&hout[idx] = o;
    } else {
        o.x = pk2(av[0], av[1]); o.y = pk2(av[2], av[3]);
        o.z = pk2(av[4], av[5]); o.w = pk2(av[6], av[7]);
        *(uint4*)&acc[idx] = o;
    }
}

// ---------- GEMM2: out = h16 @ W2 + b2 ----------
__global__ __launch_bounds__(256) void k_gemm2(const __half* __restrict__ h,
                                               const float* __restrict__ W2,
                                               const float* __restrict__ b2,
                                               float* __restrict__ out) {
    __shared__ float W2s[64 * 32];
    __shared__ float b2s[32];
    int t = threadIdx.x;
    for (int i = t * 4; i < 64 * 32; i += 256 * 4)
        *(float4*)&W2s[i] = *(const float4*)&W2[i];
    if (t < 32) b2s[t] = b2[t];
    __syncthreads();

    int gid = blockIdx.x * 256 + t;
    int row = gid >> 3;
    int c4 = (t & 7) * 4;
    if (row >= NN) return;
    const __half* hr = h + (size_t)row * 64;
    float4 acc = *(const float4*)&b2s[c4];
#pragma unroll
    for (int k8 = 0; k8 < 8; ++k8) {
        uint4 raw = *(const uint4*)&hr[k8 * 8];
        float2 a01 = up2(raw.x), a23 = up2(raw.y), a45 = up2(raw.z), a67 = up2(raw.w);
        float a[8] = {a01.x, a01.y, a23.x, a23.y, a45.x, a45.y, a67.x, a67.y};
#pragma unroll
        for (int j = 0; j < 8; ++j) {
            float4 w = *(const float4*)&W2s[(k8 * 8 + j) * 32 + c4];
            acc.x += a[j] * w.x;
            acc.y += a[j] * w.y;
            acc.z += a[j] * w.z;
            acc.w += a[j] * w.w;
        }
    }
    *(float4*)&out[(size_t)row * 32 + c4] = acc;
}

extern "C" void kernel_launch(void* const* d_in, const int* in_sizes, int n_in,
                              void* d_out, int out_size, void* d_ws, size_t ws_size,
                              hipStream_t stream) {
    const float* x      = (const float*)d_in[0];
    const int*   ei     = (const int*)d_in[1];
    const float* W1     = (const float*)d_in[2];
    const float* b1     = (const float*)d_in[3];
    const float* coeffs = (const float*)d_in[4];
    const float* W2     = (const float*)d_in[5];
    const float* b2     = (const float*)d_in[6];
    float* out = (float*)d_out;

    char* ws = (char*)d_ws;
    size_t off = 0;
    auto alloc = [&](size_t bytes) { void* p = ws + off; off += (bytes + 255) & ~(size_t)255; return p; };
    int*      cnt    = (int*)alloc(NN * 4);
    int*      cursor = (int*)alloc((NN + 1) * 4);
    int*      bsum   = (int*)alloc(NBLK * 4);
    float*    dinv   = (float*)alloc(NN * 4);
    int*      csr    = (int*)alloc((size_t)NE * 4);
    int2*     bkt    = (int2*)alloc((size_t)NE * 8);
    int*      bcur   = (int*)alloc(NB * 4);
    _Float16* W1T    = (_Float16*)alloc(256 * 64 * 2);
    __half*   h16    = (__half*)alloc((size_t)NN * HID * 2);
    __half*   bufA   = (__half*)alloc((size_t)NN * HID * 2);
    __half*   bufB   = (__half*)alloc((size_t)NN * HID * 2);
    __half*   bufC   = (__half*)alloc((size_t)NN * HID * 2);
    __half*   accb   = (__half*)alloc((size_t)NN * HID * 2);

    const int BN = (NN + 255) / 256;
    const int BE = (NE + 255) / 256;
    const int BP = (NN + 31) / 32;          // 8 nodes/wave, 4 waves/block -> 32 nodes/block

    // --- CSR build (bucketed) ---
    k_zero<<<BN, 256, 0, stream>>>(cnt);
    k_hist<<<BE, 256, 0, stream>>>(ei, cnt);
    k_dinv<<<BN, 256, 0, stream>>>(cnt, dinv);
    k_scan1<<<NBLK, SCAN_BLK, 0, stream>>>(cnt, cursor, bsum);
    k_scan2<<<1, 128, 0, stream>>>(bsum);
    k_scan3<<<NBLK, SCAN_BLK, 0, stream>>>(cursor, bsum);
    k_binit<<<(NB + 255) / 256, 256, 0, stream>>>(cursor, bcur);
    k_bucket<<<BE, 256, 0, stream>>>(ei, bcur, bkt);
    k_build<<<NB, 256, 0, stream>>>(cursor, bkt, csr);

    // --- h~ = dinv * relu(x @ W1 + b1) via MFMA ---
    k_prepw1<<<64, 256, 0, stream>>>(W1, W1T);
    k_gemm1<<<(NN + 63) / 64, 256, 0, stream>>>(x, W1T, b1, dinv, h16);

    __half* rot[4] = {h16, bufA, bufB, bufC};

    for (int l = 0; l < 2; ++l) {
        int cbase = l * (KORD + 1);
        k_prop<<<BP, 256, 0, stream>>>(cursor, csr, rot[0], rot[0], dinv,
                                       rot[1], accb, h16, 1.0f, 0.0f, 0.0f,
                                       coeffs, cbase, 1, 1, 0, 0);
        for (int k = 2; k <= KORD; ++k) {
            __half* dst = rot[k & 3];
            const __half* s1 = rot[(k - 1) & 3];
            const __half* s0 = rot[(k - 2) & 3];
            double n = k - 1, a = 0.5, b = 0.5;
            double An = (2*n + a + b + 1) * (2*n + a + b + 2) / (2 * (n + 1) * (n + a + b + 1));
            double Bn = (a*a - b*b) * (2*n + a + b + 1) / (2 * (n + 1) * (n + a + b + 1) * (2*n + a + b));
            double Cn = (n + a) * (n + b) * (2*n + a + b + 2) / ((n + 1) * (n + a + b + 1) * (2*n + a + b));
            k_prop<<<BP, 256, 0, stream>>>(cursor, csr, s1, s0, dinv,
                                           dst, accb, h16, (float)An, (float)Bn, (float)Cn,
                                           coeffs, cbase, k, 0,
                                           (k == KORD) ? 1 : 0, l);
        }
    }

    // out = h @ W2 + b2
    k_gemm2<<<(NN * 8 + 255) / 256, 256, 0, stream>>>(h16, W2, b2, out);
}

// Round 10
// 1174.298 us; speedup vs baseline: 1.3209x; 1.3209x over previous
//
#include <hip/hip_runtime.h>
#include <hip/hip_fp16.h>

#define NN 100000
#define NE 1600000
#define KORD 10
#define HID 64
#define SCAN_BLK 1024
#define NBLK ((NN + SCAN_BLK - 1) / SCAN_BLK)   // 98

typedef _Float16 half8v __attribute__((ext_vector_type(8)));
typedef _Float16 half4v __attribute__((ext_vector_type(4)));
typedef float float4v __attribute__((ext_vector_type(4)));

__device__ __forceinline__ float2 up2(unsigned u) {
    __half2 hh = *(__half2*)&u;
    return __half22float2(hh);
}
__device__ __forceinline__ unsigned pk2(float a, float b) {
    __half2 hh = __floats2half2_rn(a, b);
    return *(unsigned*)&hh;
}

// ---------------- degree / scan ----------------
__global__ __launch_bounds__(256) void k_zero(int* __restrict__ cnt,
                                              int* __restrict__ dhist) {
    int i = blockIdx.x * 256 + threadIdx.x;
    if (i < NN) cnt[i] = 0;
    if (i < 64) dhist[i] = 0;
}

__global__ __launch_bounds__(256) void k_hist(const int* __restrict__ ei,
                                              int* __restrict__ cnt) {
    int e = blockIdx.x * 256 + threadIdx.x;
    if (e < NE) atomicAdd(&cnt[ei[NE + e]], 1);
}

__global__ __launch_bounds__(256) void k_dinv(const int* __restrict__ cnt,
                                              float* __restrict__ dinv) {
    int i = blockIdx.x * 256 + threadIdx.x;
    if (i < NN) dinv[i] = rsqrtf((float)(cnt[i] + 1));   // +1 self-loop
}

__global__ __launch_bounds__(SCAN_BLK) void k_scan1(const int* __restrict__ cnt,
                                                    int* __restrict__ cursor,
                                                    int* __restrict__ bsum) {
    __shared__ int tmp[SCAN_BLK];
    int t = threadIdx.x;
    int g = blockIdx.x * SCAN_BLK + t;
    int v = (g < NN) ? cnt[g] : 0;
    tmp[t] = v;
    __syncthreads();
    int x = v;
    for (int off = 1; off < SCAN_BLK; off <<= 1) {
        int y = (t >= off) ? tmp[t - off] : 0;
        __syncthreads();
        x += y;
        tmp[t] = x;
        __syncthreads();
    }
    if (g < NN) cursor[g] = x - v;
    if (t == SCAN_BLK - 1) bsum[blockIdx.x] = x;
}

__global__ __launch_bounds__(128) void k_scan2(int* __restrict__ bsum) {
    __shared__ int tmp[128];
    int t = threadIdx.x;
    int v = (t < NBLK) ? bsum[t] : 0;
    tmp[t] = v;
    __syncthreads();
    int x = v;
    for (int off = 1; off < 128; off <<= 1) {
        int y = (t >= off) ? tmp[t - off] : 0;
        __syncthreads();
        x += y;
        tmp[t] = x;
        __syncthreads();
    }
    if (t < NBLK) bsum[t] = x - v;
}

__global__ __launch_bounds__(SCAN_BLK) void k_scan3(int* __restrict__ cursor,
                                                    const int* __restrict__ bsum,
                                                    int* __restrict__ ccur) {
    int g = blockIdx.x * SCAN_BLK + threadIdx.x;
    if (g < NN) {
        int v = cursor[g] + bsum[blockIdx.x];
        cursor[g] = v;
        ccur[g] = v;                      // mutable copy for the scatter
    }
    if (g == 0) cursor[NN] = NE;          // sentinel end offset
}

// direct weightless scatter: csr[pos] = source row
__global__ __launch_bounds__(256) void k_scatter(const int* __restrict__ ei,
                                                 int* __restrict__ ccur,
                                                 int* __restrict__ csr) {
    int e = blockIdx.x * 256 + threadIdx.x;
    if (e >= NE) return;
    int r = ei[e], c = ei[NE + e];
    int pos = atomicAdd(&ccur[c], 1);
    csr[pos] = r;
}

// ---------------- degree-sorted node permutation ----------------
__global__ __launch_bounds__(256) void k_dhist(const int* __restrict__ cnt,
                                               int* __restrict__ dhist) {
    __shared__ int lh[64];
    int t = threadIdx.x;
    if (t < 64) lh[t] = 0;
    __syncthreads();
    int i = blockIdx.x * 256 + t;
    if (i < NN) atomicAdd(&lh[min(cnt[i], 63)], 1);
    __syncthreads();
    if (t < 64 && lh[t]) atomicAdd(&dhist[t], lh[t]);
}

__global__ void k_dscan(int* __restrict__ dhist) {   // 64 threads, exclusive scan
    __shared__ int tmp[64];
    int t = threadIdx.x;
    int v = dhist[t];
    tmp[t] = v;
    __syncthreads();
    int x = v;
    for (int off = 1; off < 64; off <<= 1) {
        int y = (t >= off) ? tmp[t - off] : 0;
        __syncthreads();
        x += y;
        tmp[t] = x;
        __syncthreads();
    }
    dhist[t] = x - v;
}

__global__ __launch_bounds__(256) void k_dperm(const int* __restrict__ cnt,
                                               int* __restrict__ dhist,
                                               int* __restrict__ perm) {
    __shared__ int lh[64], lb[64];
    int t = threadIdx.x;
    if (t < 64) lh[t] = 0;
    __syncthreads();
    int i = blockIdx.x * 256 + t;
    int b = 0, my = 0;
    if (i < NN) { b = min(cnt[i], 63); my = atomicAdd(&lh[b], 1); }
    __syncthreads();
    if (t < 64) lb[t] = lh[t] ? atomicAdd(&dhist[t], lh[t]) : 0;
    __syncthreads();
    if (i < NN) perm[lb[b] + my] = i;
}

// zero sentinel row NN of the 4 rotation buffers
__global__ __launch_bounds__(256) void k_zrow(__half* __restrict__ a, __half* __restrict__ b,
                                              __half* __restrict__ c, __half* __restrict__ d) {
    int t = threadIdx.x;
    __half z = __float2half(0.f);
    size_t base = (size_t)NN * HID;
    if (t < 64)       a[base + t] = z;
    else if (t < 128) b[base + (t - 64)] = z;
    else if (t < 192) c[base + (t - 128)] = z;
    else              d[base + (t - 192)] = z;
}

// ---------- W1 transpose + fp16 cast ----------
__global__ __launch_bounds__(256) void k_prepw1(const float* __restrict__ W1,
                                                _Float16* __restrict__ W1T) {
    int f = blockIdx.x * 256 + threadIdx.x;
    int n = f >> 8, k = f & 255;
    W1T[f] = (_Float16)W1[k * 64 + n];
}

// ---------- GEMM1 via MFMA: h~ = dinv * relu(x @ W1 + b1) ----------
#define G1K 128
#define G1S 136
__global__ __launch_bounds__(256) void k_gemm1(const float* __restrict__ x,
                                               const _Float16* __restrict__ W1T,
                                               const float* __restrict__ b1,
                                               const float* __restrict__ dinv,
                                               __half* __restrict__ h) {
    __shared__ _Float16 A_lds[64 * G1S];
    __shared__ _Float16 B_lds[64 * G1S];
    int t = threadIdx.x;
    int wave = t >> 6, lane = t & 63;
    int quad = lane >> 4, m16 = lane & 15;
    int row0 = blockIdx.x * 64;

    float4v acc[4];
#pragma unroll
    for (int n4 = 0; n4 < 4; ++n4) acc[n4] = (float4v){0.f, 0.f, 0.f, 0.f};

    for (int c = 0; c < 2; ++c) {
        int k0 = c * G1K;
#pragma unroll
        for (int i = 0; i < 8; ++i) {
            int f = i * 256 + t;
            int r = f >> 5, c4 = f & 31;
            int grow = row0 + r;
            float4 v = (grow < NN) ? *(const float4*)&x[(size_t)grow * 256 + k0 + c4 * 4]
                                   : make_float4(0.f, 0.f, 0.f, 0.f);
            half4v hv = {(_Float16)v.x, (_Float16)v.y, (_Float16)v.z, (_Float16)v.w};
            *(half4v*)&A_lds[r * G1S + c4 * 4] = hv;
        }
#pragma unroll
        for (int i = 0; i < 4; ++i) {
            int f = i * 256 + t;
            int n = f >> 4, k8 = f & 15;
            *(half8v*)&B_lds[n * G1S + k8 * 8] =
                *(const half8v*)&W1T[n * 256 + k0 + k8 * 8];
        }
        __syncthreads();

#pragma unroll
        for (int s = 0; s < 4; ++s) {
            half8v af = *(const half8v*)&A_lds[(wave * 16 + m16) * G1S + s * 32 + quad * 8];
#pragma unroll
            for (int n4 = 0; n4 < 4; ++n4) {
                half8v bf = *(const half8v*)&B_lds[(n4 * 16 + m16) * G1S + s * 32 + quad * 8];
                acc[n4] = __builtin_amdgcn_mfma_f32_16x16x32_f16(af, bf, acc[n4], 0, 0, 0);
            }
        }
        __syncthreads();
    }

    float bv[4];
#pragma unroll
    for (int n4 = 0; n4 < 4; ++n4) bv[n4] = b1[n4 * 16 + m16];
#pragma unroll
    for (int r = 0; r < 4; ++r) {
        int grow = row0 + wave * 16 + quad * 4 + r;
        if (grow >= NN) continue;
        float dv = dinv[grow];
#pragma unroll
        for (int n4 = 0; n4 < 4; ++n4) {
            float v = dv * fmaxf(acc[n4][r] + bv[n4], 0.f);
            h[(size_t)grow * 64 + n4 * 16 + m16] = __float2half(v);
        }
    }
}

// ---------- fused propagation + Jacobi combine ----------
// 8 nodes/wave via degree-sorted perm; 4 branchless gather streams per lane
// (sentinel zero-row NN absorbs padded iterations).
__global__ __launch_bounds__(256) void k_prop(const int* __restrict__ cursor,   // begin offsets, cursor[NN]=NE
                                              const int* __restrict__ csr,
                                              const int* __restrict__ perm,
                                              const __half* __restrict__ src,
                                              const __half* __restrict__ t0,
                                              const float* __restrict__ dinv,
                                              __half* __restrict__ dst,
                                              __half* __restrict__ acc,
                                              __half* __restrict__ hout,
                                              float An, float Bn, float Cn,
                                              const float* __restrict__ coeffs,
                                              int cbase, int kidx, int init,
                                              int finalize, int unscale) {
    int slot = ((blockIdx.x * 256 + threadIdx.x) >> 6) * 8 + ((threadIdx.x & 63) >> 3);
    int ch8 = (threadIdx.x & 7) * 8;
    bool valid = slot < NN;
    int node = valid ? perm[slot] : 0;
    int beg = valid ? cursor[node] : 0;
    int end = valid ? cursor[node + 1] : 0;

    int len = end - beg;
    int q = len >> 2;
    int j0 = beg,          e0 = beg + q;
    int j1 = e0,           e1 = beg + 2 * q;
    int j2 = e1,           e2 = beg + 3 * q;
    int j3 = e2,           e3 = end;

    float p[8];
#pragma unroll
    for (int i = 0; i < 8; ++i) p[i] = 0.f;

    while (__any(j3 < e3)) {
        int a0 = (j0 < e0) ? j0 : 0;
        int a1 = (j1 < e1) ? j1 : 0;
        int a2 = (j2 < e2) ? j2 : 0;
        int a3 = (j3 < e3) ? j3 : 0;
        int v0 = csr[a0], v1 = csr[a1], v2 = csr[a2], v3 = csr[a3];
        int r0 = (j0 < e0) ? v0 : NN;
        int r1 = (j1 < e1) ? v1 : NN;
        int r2 = (j2 < e2) ? v2 : NN;
        int r3 = (j3 < e3) ? v3 : NN;
        uint4 u0 = *(const uint4*)&src[(size_t)r0 * HID + ch8];
        uint4 u1 = *(const uint4*)&src[(size_t)r1 * HID + ch8];
        uint4 u2 = *(const uint4*)&src[(size_t)r2 * HID + ch8];
        uint4 u3 = *(const uint4*)&src[(size_t)r3 * HID + ch8];
        {
            float2 f0 = up2(u0.x), f1 = up2(u0.y), f2 = up2(u0.z), f3 = up2(u0.w);
            p[0] += f0.x; p[1] += f0.y; p[2] += f1.x; p[3] += f1.y;
            p[4] += f2.x; p[5] += f2.y; p[6] += f3.x; p[7] += f3.y;
        }
        {
            float2 f0 = up2(u1.x), f1 = up2(u1.y), f2 = up2(u1.z), f3 = up2(u1.w);
            p[0] += f0.x; p[1] += f0.y; p[2] += f1.x; p[3] += f1.y;
            p[4] += f2.x; p[5] += f2.y; p[6] += f3.x; p[7] += f3.y;
        }
        {
            float2 f0 = up2(u2.x), f1 = up2(u2.y), f2 = up2(u2.z), f3 = up2(u2.w);
            p[0] += f0.x; p[1] += f0.y; p[2] += f1.x; p[3] += f1.y;
            p[4] += f2.x; p[5] += f2.y; p[6] += f3.x; p[7] += f3.y;
        }
        {
            float2 f0 = up2(u3.x), f1 = up2(u3.y), f2 = up2(u3.z), f3 = up2(u3.w);
            p[0] += f0.x; p[1] += f0.y; p[2] += f1.x; p[3] += f1.y;
            p[4] += f2.x; p[5] += f2.y; p[6] += f3.x; p[7] += f3.y;
        }
        ++j0; ++j1; ++j2; ++j3;
    }

    if (!valid) return;
    size_t idx = (size_t)node * HID + ch8;
    float dv = dinv[node];
    float dv2 = dv * dv;

    uint4 sr = *(const uint4*)&src[idx];
    float2 s01 = up2(sr.x), s23 = up2(sr.y), s45 = up2(sr.z), s67 = up2(sr.w);
    float sv[8] = {s01.x, s01.y, s23.x, s23.y, s45.x, s45.y, s67.x, s67.y};

    uint4 tr = *(const uint4*)&t0[idx];
    float2 t01 = up2(tr.x), t23 = up2(tr.y), t45 = up2(tr.z), t67 = up2(tr.w);
    float tv[8] = {t01.x, t01.y, t23.x, t23.y, t45.x, t45.y, t67.x, t67.y};

    float v[8];
#pragma unroll
    for (int i = 0; i < 8; ++i)
        v[i] = An * dv2 * (p[i] + sv[i]) + Bn * sv[i] - Cn * tv[i];

    if (!finalize) {
        uint4 o;
        o.x = pk2(v[0], v[1]); o.y = pk2(v[2], v[3]);
        o.z = pk2(v[4], v[5]); o.w = pk2(v[6], v[7]);
        *(uint4*)&dst[idx] = o;
    }

    float ck = coeffs[cbase + kidx];
    float av[8];
    if (init) {
        float c0 = coeffs[cbase];
#pragma unroll
        for (int i = 0; i < 8; ++i) av[i] = c0 * sv[i];
    } else {
        uint4 ar = *(const uint4*)&acc[idx];
        float2 a01 = up2(ar.x), a23 = up2(ar.y), a45 = up2(ar.z), a67 = up2(ar.w);
        av[0] = a01.x; av[1] = a01.y; av[2] = a23.x; av[3] = a23.y;
        av[4] = a45.x; av[5] = a45.y; av[6] = a67.x; av[7] = a67.y;
    }
#pragma unroll
    for (int i = 0; i < 8; ++i) av[i] += ck * v[i];

    uint4 o;
    if (finalize) {
        float s = unscale ? (1.0f / dv) : 1.0f;
        o.x = pk2(s * fmaxf(av[0], 0.f), s * fmaxf(av[1], 0.f));
        o.y = pk2(s * fmaxf(av[2], 0.f), s * fmaxf(av[3], 0.f));
        o.z = pk2(s * fmaxf(av[4], 0.f), s * fmaxf(av[5], 0.f));
        o.w = pk2(s * fmaxf(av[6], 0.f), s * fmaxf(av[7], 0.f));
        *(uint4*)&hout[idx] = o;
    } else {
        o.x = pk2(av[0], av[1]); o.y = pk2(av[2], av[3]);
        o.z = pk2(av[4], av[5]); o.w = pk2(av[6], av[7]);
        *(uint4*)&acc[idx] = o;
    }
}

// ---------- GEMM2: out = h16 @ W2 + b2 ----------
__global__ __launch_bounds__(256) void k_gemm2(const __half* __restrict__ h,
                                               const float* __restrict__ W2,
                                               const float* __restrict__ b2,
                                               float* __restrict__ out) {
    __shared__ float W2s[64 * 32];
    __shared__ float b2s[32];
    int t = threadIdx.x;
    for (int i = t * 4; i < 64 * 32; i += 256 * 4)
        *(float4*)&W2s[i] = *(const float4*)&W2[i];
    if (t < 32) b2s[t] = b2[t];
    __syncthreads();

    int gid = blockIdx.x * 256 + t;
    int row = gid >> 3;
    int c4 = (t & 7) * 4;
    if (row >= NN) return;
    const __half* hr = h + (size_t)row * 64;
    float4 acc = *(const float4*)&b2s[c4];
#pragma unroll
    for (int k8 = 0; k8 < 8; ++k8) {
        uint4 raw = *(const uint4*)&hr[k8 * 8];
        float2 a01 = up2(raw.x), a23 = up2(raw.y), a45 = up2(raw.z), a67 = up2(raw.w);
        float a[8] = {a01.x, a01.y, a23.x, a23.y, a45.x, a45.y, a67.x, a67.y};
#pragma unroll
        for (int j = 0; j < 8; ++j) {
            float4 w = *(const float4*)&W2s[(k8 * 8 + j) * 32 + c4];
            acc.x += a[j] * w.x;
            acc.y += a[j] * w.y;
            acc.z += a[j] * w.z;
            acc.w += a[j] * w.w;
        }
    }
    *(float4*)&out[(size_t)row * 32 + c4] = acc;
}

extern "C" void kernel_launch(void* const* d_in, const int* in_sizes, int n_in,
                              void* d_out, int out_size, void* d_ws, size_t ws_size,
                              hipStream_t stream) {
    const float* x      = (const float*)d_in[0];
    const int*   ei     = (const int*)d_in[1];
    const float* W1     = (const float*)d_in[2];
    const float* b1     = (const float*)d_in[3];
    const float* coeffs = (const float*)d_in[4];
    const float* W2     = (const float*)d_in[5];
    const float* b2     = (const float*)d_in[6];
    float* out = (float*)d_out;

    char* ws = (char*)d_ws;
    size_t off = 0;
    auto alloc = [&](size_t bytes) { void* p = ws + off; off += (bytes + 255) & ~(size_t)255; return p; };
    int*      cnt    = (int*)alloc(NN * 4);
    int*      cursor = (int*)alloc((NN + 1) * 4);
    int*      ccur   = (int*)alloc(NN * 4);
    int*      bsum   = (int*)alloc(NBLK * 4);
    float*    dinv   = (float*)alloc(NN * 4);
    int*      csr    = (int*)alloc((size_t)NE * 4);
    int*      dhist  = (int*)alloc(64 * 4);
    int*      perm   = (int*)alloc(NN * 4);
    _Float16* W1T    = (_Float16*)alloc(256 * 64 * 2);
    __half*   h16    = (__half*)alloc((size_t)(NN + 1) * HID * 2);   // +1 sentinel row
    __half*   bufA   = (__half*)alloc((size_t)(NN + 1) * HID * 2);
    __half*   bufB   = (__half*)alloc((size_t)(NN + 1) * HID * 2);
    __half*   bufC   = (__half*)alloc((size_t)(NN + 1) * HID * 2);
    __half*   accb   = (__half*)alloc((size_t)NN * HID * 2);

    const int BN = (NN + 255) / 256;
    const int BE = (NE + 255) / 256;
    const int BP = (NN + 31) / 32;          // 8 nodes/wave, 4 waves/block

    // --- CSR build ---
    k_zero<<<BN, 256, 0, stream>>>(cnt, dhist);
    k_hist<<<BE, 256, 0, stream>>>(ei, cnt);
    k_dinv<<<BN, 256, 0, stream>>>(cnt, dinv);
    k_scan1<<<NBLK, SCAN_BLK, 0, stream>>>(cnt, cursor, bsum);
    k_scan2<<<1, 128, 0, stream>>>(bsum);
    k_scan3<<<NBLK, SCAN_BLK, 0, stream>>>(cursor, bsum, ccur);
    k_scatter<<<BE, 256, 0, stream>>>(ei, ccur, csr);

    // --- degree-sorted node permutation ---
    k_dhist<<<BN, 256, 0, stream>>>(cnt, dhist);
    k_dscan<<<1, 64, 0, stream>>>(dhist);
    k_dperm<<<BN, 256, 0, stream>>>(cnt, dhist, perm);
    k_zrow<<<1, 256, 0, stream>>>(h16, bufA, bufB, bufC);

    // --- h~ = dinv * relu(x @ W1 + b1) via MFMA ---
    k_prepw1<<<64, 256, 0, stream>>>(W1, W1T);
    k_gemm1<<<(NN + 63) / 64, 256, 0, stream>>>(x, W1T, b1, dinv, h16);

    __half* rot[4] = {h16, bufA, bufB, bufC};

    for (int l = 0; l < 2; ++l) {
        int cbase = l * (KORD + 1);
        k_prop<<<BP, 256, 0, stream>>>(cursor, csr, perm, rot[0], rot[0], dinv,
                                       rot[1], accb, h16, 1.0f, 0.0f, 0.0f,
                                       coeffs, cbase, 1, 1, 0, 0);
        for (int k = 2; k <= KORD; ++k) {
            __half* dst = rot[k & 3];
            const __half* s1 = rot[(k - 1) & 3];
            const __half* s0 = rot[(k - 2) & 3];
            double n = k - 1, a = 0.5, b = 0.5;
            double An = (2*n + a + b + 1) * (2*n + a + b + 2) / (2 * (n + 1) * (n + a + b + 1));
            double Bn = (a*a - b*b) * (2*n + a + b + 1) / (2 * (n + 1) * (n + a + b + 1) * (2*n + a + b));
            double Cn = (n + a) * (n + b) * (2*n + a + b + 2) / ((n + 1) * (n + a + b + 1) * (2*n + a + b));
            k_prop<<<BP, 256, 0, stream>>>(cursor, csr, perm, s1, s0, dinv,
                                           dst, accb, h16, (float)An, (float)Bn, (float)Cn,
                                           coeffs, cbase, k, 0,
                                           (k == KORD) ? 1 : 0, l);
        }
    }

    // out = h @ W2 + b2
    k_gemm2<<<(NN * 8 + 255) / 256, 256, 0, stream>>>(h16, W2, b2, out);
}